// Round 2
// baseline (3174.237 us; speedup 1.0000x reference)
//
#include <hip/hip_runtime.h>

#define NENT 40000
#define NB 128
#define NOPS 12
#define EPO 300000
#define NTOT (NOPS * EPO)
#define NRANK 3
#define NPASS 8
#define CP 16   // batch columns per pass

typedef float v2f __attribute__((ext_vector_type(2)));
typedef int   v2i __attribute__((ext_vector_type(2)));

// ---------------- CSR build (fused src+dst) ----------------
__global__ void hist2_kernel(const int* __restrict__ src, const int* __restrict__ dst,
                             int* __restrict__ cntS, int* __restrict__ cntD) {
    int i = blockIdx.x * 256 + threadIdx.x;
    if (i < NTOT) {
        atomicAdd(&cntS[src[i]], 1);
        atomicAdd(&cntD[dst[i]], 1);
    }
}

__global__ void scan2_kernel(const int* __restrict__ cnt_all, int* __restrict__ rp_all) {
    const int* cnt = cnt_all + blockIdx.x * NENT;
    int* rp = rp_all + blockIdx.x * (NENT + 1);
    __shared__ int part[1024];
    int t = threadIdx.x;
    int beg = t * 40;
    int end = min(NENT, beg + 40);
    int s = 0;
    for (int i = beg; i < end; ++i) s += cnt[i];
    part[t] = s;
    __syncthreads();
    for (int offs = 1; offs < 1024; offs <<= 1) {
        int add = (t >= offs) ? part[t - offs] : 0;
        __syncthreads();
        part[t] += add;
        __syncthreads();
    }
    int run = part[t] - s;
    for (int i = beg; i < end; ++i) { rp[i] = run; run += cnt[i]; }
    if (t == 1023) rp[NENT] = part[1023];
}

__global__ void scatter2_kernel(const int* __restrict__ src, const int* __restrict__ dst,
                                const float* __restrict__ val,
                                const int* __restrict__ rpS, const int* __restrict__ rpD,
                                int* __restrict__ fillS, int* __restrict__ fillD,
                                int2* __restrict__ eS, int2* __restrict__ eD) {
    int i = blockIdx.x * 256 + threadIdx.x;
    if (i >= NTOT) return;
    int s = src[i], d = dst[i];
    int op = i / EPO;
    int v = __float_as_int(val[i]);
    int ps = atomicAdd(&fillS[s], 1);
    eS[rpS[s] + ps] = make_int2(d | (op << 16), v);
    int pd = atomicAdd(&fillD[d], 1);
    eD[rpD[d] + pd] = make_int2(s | (op << 16), v);
}

// ---------------- LSTM ----------------
__global__ void zx_kernel(const int* __restrict__ queries, const float* __restrict__ emb,
                          const float* __restrict__ Wih_f, const float* __restrict__ bih_f,
                          const float* __restrict__ bhh_f,
                          const float* __restrict__ Wih_b, const float* __restrict__ bih_b,
                          const float* __restrict__ bhh_b,
                          float* __restrict__ zx) {
    int combo = blockIdx.x >> 7;
    int b = blockIdx.x & 127;
    int dir = combo / 3, r = combo % 3;
    const float* Wih = (dir ? Wih_b : Wih_f) + r * 512 * 128;
    const float* bih = (dir ? bih_b : bih_f) + r * 512;
    const float* bhh = (dir ? bhh_b : bhh_f) + r * 512;
    __shared__ float x[128];
    int u = threadIdx.x;
    x[u] = emb[queries[b] * 128 + u];
    __syncthreads();
    const float* W0p = Wih + u * 128;
    const float* W1p = Wih + (128 + u) * 128;
    const float* W2p = Wih + (256 + u) * 128;
    const float* W3p = Wih + (384 + u) * 128;
    float a0 = 0.f, a1 = 0.f, a2 = 0.f, a3 = 0.f;
    for (int d = 0; d < 128; ++d) {
        float xv = x[d];
        a0 = fmaf(xv, W0p[d], a0);
        a1 = fmaf(xv, W1p[d], a1);
        a2 = fmaf(xv, W2p[d], a2);
        a3 = fmaf(xv, W3p[d], a3);
    }
    float* o = zx + (size_t)(combo * 128 + b) * 512;
    o[u]       = a0 + bih[u]       + bhh[u];
    o[128 + u] = a1 + bih[128 + u] + bhh[128 + u];
    o[256 + u] = a2 + bih[256 + u] + bhh[256 + u];
    o[384 + u] = a3 + bih[384 + u] + bhh[384 + u];
}

// all 3 steps in one kernel; recurrence is block-local (block owns all 128 hidden units)
__global__ void lstm_kernel(const float* __restrict__ Whh_f, const float* __restrict__ Whh_b,
                            const float* __restrict__ zx, float* __restrict__ hstate) {
    int combo = blockIdx.x >> 7;
    int b = blockIdx.x & 127;
    int dir = combo / 3, r = combo % 3;
    const float* Whh = (dir ? Whh_b : Whh_f) + r * 512 * 128;
    __shared__ float h[128];
    int u = threadIdx.x;
    const float* z = zx + (size_t)(combo * 128 + b) * 512;
    float zi0 = z[u], zf0 = z[128 + u], zg0 = z[256 + u], zo0 = z[384 + u];
    const float* Wi = Whh + u * 128;
    const float* Wf = Whh + (128 + u) * 128;
    const float* Wg = Whh + (256 + u) * 128;
    const float* Wo = Whh + (384 + u) * 128;
    float c = 0.f;
    h[u] = 0.f;
    for (int s = 0; s < 3; ++s) {
        __syncthreads();
        float a0 = 0.f, a1 = 0.f, a2 = 0.f, a3 = 0.f;
        for (int d = 0; d < 128; ++d) {
            float hv = h[d];
            a0 = fmaf(hv, Wi[d], a0);
            a1 = fmaf(hv, Wf[d], a1);
            a2 = fmaf(hv, Wg[d], a2);
            a3 = fmaf(hv, Wo[d], a3);
        }
        float ig = 1.f / (1.f + expf(-(zi0 + a0)));
        float fg = 1.f / (1.f + expf(-(zf0 + a1)));
        float gg = tanhf(zg0 + a2);
        float og = 1.f / (1.f + expf(-(zo0 + a3)));
        c = fg * c + ig * gg;
        float hn = og * tanhf(c);
        __syncthreads();
        h[u] = hn;
        hstate[(size_t)((combo * 3 + s) * 128 + b) * 128 + u] = hn;
    }
}

__global__ void attn_kernel(const float* __restrict__ hstate, const float* __restrict__ W0,
                            const float* __restrict__ b0, float* __restrict__ attn) {
    int r = blockIdx.x / 3, t = blockIdx.x % 3;
    __shared__ float W0s[256 * 13];
    for (int idx = threadIdx.x; idx < 256 * 13; idx += 128) W0s[idx] = W0[idx];
    __syncthreads();
    int b = threadIdx.x;
    float acc[13];
    for (int k = 0; k < 13; ++k) acc[k] = b0[k];
    const float* hf = hstate + (size_t)(((0 * 3 + r) * 3 + t) * 128 + b) * 128;
    const float* hb = hstate + (size_t)(((1 * 3 + r) * 3 + (2 - t)) * 128 + b) * 128;
    for (int u = 0; u < 128; ++u) {
        float v = hf[u];
        for (int k = 0; k < 13; ++k) acc[k] = fmaf(v, W0s[u * 13 + k], acc[k]);
    }
    for (int u = 0; u < 128; ++u) {
        float v = hb[u];
        for (int k = 0; k < 13; ++k) acc[k] = fmaf(v, W0s[(128 + u) * 13 + k], acc[k]);
    }
    float m = acc[0];
    for (int k = 1; k < 13; ++k) m = fmaxf(m, acc[k]);
    float e[13];
    float sum = 0.f;
    for (int k = 0; k < 13; ++k) { e[k] = expf(acc[k] - m); sum += e[k]; }
    float inv = 1.f / sum;
    float* ao = attn + (size_t)(r * 3 + t) * 13 * 128;
    for (int k = 0; k < 13; ++k) ao[k * 128 + b] = e[k] * inv;
}

// ---------------- steps 0+1, sparse expansion; writes pass-major mem[r][p][j][c] ----------------
__global__ void fused01_kernel(const int* __restrict__ heads, const float* __restrict__ attn,
                               const int* __restrict__ rpS, const int2* __restrict__ edgesS,
                               float* __restrict__ mem2) {
    int r = blockIdx.y;
    int b = blockIdx.x;
    __shared__ float c0s[13], c1s[13];
    if (threadIdx.x < 13) {
        c0s[threadIdx.x] = attn[(size_t)((r * 3 + 0) * 13 + threadIdx.x) * 128 + b];
        c1s[threadIdx.x] = attn[(size_t)((r * 3 + 1) * 13 + threadIdx.x) * 128 + b];
    }
    __syncthreads();
    int h = heads[b];
    int beg = rpS[h], end = rpS[h + 1];
    int nE = end - beg + 1;
    float* mem = mem2 + ((size_t)(r * NPASS + (b >> 4)) * NENT) * CP + (b & 15);
    for (int ent = threadIdx.x; ent < nE; ent += 128) {
        int i; float wv;
        if (ent == 0) { i = h; wv = c0s[12]; }
        else {
            int2 e = edgesS[beg + ent - 1];
            i = e.x & 0xFFFF;
            wv = __int_as_float(e.y) * c0s[e.x >> 16];
        }
        atomicAdd(&mem[(size_t)i * CP], c1s[12] * wv);
        int fb = rpS[i], fe = rpS[i + 1];
        for (int f = fb; f < fe; ++f) {
            int2 e2 = edgesS[f];
            atomicAdd(&mem[(size_t)(e2.x & 0xFFFF) * CP],
                      __int_as_float(e2.y) * c1s[e2.x >> 16] * wv);
        }
    }
}

// ---------------- step 2, dense gather over L2-resident 16-col pass slabs ----------------
__global__ __launch_bounds__(256) void dense_kernel(const float* __restrict__ attn,
                                                    const int* __restrict__ rpD,
                                                    const int2* __restrict__ edgesD,
                                                    const float* __restrict__ in,
                                                    float* __restrict__ out) {
    int p = blockIdx.y;
    int r = blockIdx.z;
    __shared__ float cs[13 * CP];
    if (threadIdx.x < 13 * CP) {
        int op = threadIdx.x / CP, c = threadIdx.x % CP;
        cs[threadIdx.x] = attn[(size_t)((r * 3 + 2) * 13 + op) * 128 + p * CP + c];
    }
    __syncthreads();
    int wave = threadIdx.x >> 6, lane = threadIdx.x & 63;
    int g = lane >> 3;          // 8 j-groups per wave
    int c2 = (lane & 7) * 2;    // 2 cols per lane -> 16 cols
    int j = blockIdx.x * 32 + wave * 8 + g;
    const float* inr = in + (size_t)(r * NPASS + p) * NENT * CP;
    float* outr = out + (size_t)(r * NPASS + p) * NENT * CP;
    int kb = rpD[j];
    int len = rpD[j + 1] - kb;
    int lm = len;
    lm = max(lm, __shfl_xor(lm, 8));
    lm = max(lm, __shfl_xor(lm, 16));
    lm = max(lm, __shfl_xor(lm, 32));
    v2f cid = *(const v2f*)&cs[12 * CP + c2];
    v2f mi = *(const v2f*)(inr + (size_t)j * CP + c2);
    v2f acc;
    acc.x = cid.x * mi.x;
    acc.y = cid.y * mi.y;
    for (int i = 0; i < lm; ++i) {
        if (i < len) {
            v2i e = __builtin_nontemporal_load((const v2i*)&edgesD[kb + i]);
            int srcv = e.x & 0xFFFF;
            float v = __int_as_float(e.y);
            v2f mm = *(const v2f*)(inr + (size_t)srcv * CP + c2);
            v2f cc = *(const v2f*)&cs[(e.x >> 16) * CP + c2];
            acc.x = fmaf(v * cc.x, mm.x, acc.x);
            acc.y = fmaf(v * cc.y, mm.y, acc.y);
        }
    }
    __builtin_nontemporal_store(acc, (v2f*)(outr + (size_t)j * CP + c2));
}

// ---------------- epilogue (pass-major reads) ----------------
__global__ void norm_kernel(const float* __restrict__ mem3, float* __restrict__ normv) {
    int p = blockIdx.y, r = blockIdx.z;
    int c = threadIdx.x & 15, jj = threadIdx.x >> 4;
    const float* m = mem3 + ((size_t)(r * NPASS + p) * NENT + (size_t)blockIdx.x * 320) * CP;
    float acc = 0.f;
    for (int j = jj; j < 320; j += 16) acc += m[(size_t)j * CP + c];
    __shared__ float red[256];
    red[threadIdx.x] = acc;
    __syncthreads();
    for (int s = 128; s >= 16; s >>= 1) {
        if (threadIdx.x < s) red[threadIdx.x] += red[threadIdx.x + s];
        __syncthreads();
    }
    if (threadIdx.x < 16) atomicAdd(&normv[r * 128 + p * CP + threadIdx.x], red[threadIdx.x]);
}

__global__ void rnorm_kernel(const float* __restrict__ normv, float* __restrict__ rnormv) {
    int i = threadIdx.x;
    rnormv[i] = 1.f / fmaxf(normv[i], 1e-20f);
}

__global__ void final_kernel(const float* __restrict__ mem3, const float* __restrict__ rnormv,
                             float* __restrict__ out) {
    __shared__ float tile[32 * 129];
    __shared__ float rn[384];
    for (int idx = threadIdx.x; idx < 384; idx += 256) rn[idx] = rnormv[idx];
    __syncthreads();
    int j0 = blockIdx.x * 32;
    for (int p = 0; p < NPASS; ++p) {
        for (int it = 0; it < 2; ++it) {
            int lin = it * 256 + threadIdx.x;
            int jj = lin >> 4, c = lin & 15;
            int b = p * CP + c;
            float s = 0.f;
            for (int r = 0; r < 3; ++r)
                s += mem3[((size_t)(r * NPASS + p) * NENT + j0 + jj) * CP + c] * rn[r * 128 + b];
            tile[jj * 129 + b] = s;
        }
    }
    __syncthreads();
    for (int it = 0; it < 16; ++it) {
        int lin = it * 256 + threadIdx.x;
        int b = lin >> 5, jj = lin & 31;
        out[(size_t)b * NENT + j0 + jj] = tile[jj * 129 + b];
    }
}

extern "C" void kernel_launch(void* const* d_in, const int* in_sizes, int n_in,
                              void* d_out, int out_size, void* d_ws, size_t ws_size,
                              hipStream_t stream) {
    const int*   queries  = (const int*)d_in[0];
    const int*   heads    = (const int*)d_in[1];
    const int*   edge_src = (const int*)d_in[2];
    const int*   edge_dst = (const int*)d_in[3];
    const float* edge_val = (const float*)d_in[4];
    const float* emb      = (const float*)d_in[5];
    const float* Wih_f    = (const float*)d_in[6];
    const float* Whh_f    = (const float*)d_in[7];
    const float* bih_f    = (const float*)d_in[8];
    const float* bhh_f    = (const float*)d_in[9];
    const float* Wih_b    = (const float*)d_in[10];
    const float* Whh_b    = (const float*)d_in[11];
    const float* bih_b    = (const float*)d_in[12];
    const float* bhh_b    = (const float*)d_in[13];
    const float* W0       = (const float*)d_in[14];
    const float* b0       = (const float*)d_in[15];
    float* out = (float*)d_out;

    char* w = (char*)d_ws;
    size_t off = 0;
    auto alloc = [&](size_t bytes) -> void* {
        off = (off + 255) & ~(size_t)255;
        void* p = w + off;
        off += bytes;
        return p;
    };
    float* attn   = (float*)alloc((size_t)NRANK * 3 * 13 * NB * sizeof(float));
    float* zx     = (float*)alloc((size_t)6 * NB * 512 * sizeof(float));
    float* hstate = (float*)alloc((size_t)6 * 3 * NB * 128 * sizeof(float));
    int*   rp2    = (int*)alloc((size_t)2 * (NENT + 1) * sizeof(int));
    int*   cnt2   = (int*)alloc((size_t)2 * NENT * sizeof(int));
    int2*  edgesS = (int2*)alloc((size_t)NTOT * sizeof(int2));
    int2*  edgesD = (int2*)alloc((size_t)NTOT * sizeof(int2));
    float* mem2   = (float*)alloc((size_t)NRANK * NENT * NB * sizeof(float));
    float* mem3   = (float*)alloc((size_t)NRANK * NENT * NB * sizeof(float));
    float* normv  = (float*)alloc((size_t)NRANK * NB * sizeof(float));
    float* rnormv = (float*)alloc((size_t)NRANK * NB * sizeof(float));

    int* rpS = rp2;
    int* rpD = rp2 + (NENT + 1);
    int* cntS = cnt2;
    int* cntD = cnt2 + NENT;

    int histGrid = (NTOT + 255) / 256;

    // CSR build (both directions in one sweep)
    hipMemsetAsync(cnt2, 0, 2 * NENT * sizeof(int), stream);
    hist2_kernel<<<histGrid, 256, 0, stream>>>(edge_src, edge_dst, cntS, cntD);
    scan2_kernel<<<2, 1024, 0, stream>>>(cnt2, rp2);
    hipMemsetAsync(cnt2, 0, 2 * NENT * sizeof(int), stream);
    scatter2_kernel<<<histGrid, 256, 0, stream>>>(edge_src, edge_dst, edge_val,
                                                  rpS, rpD, cntS, cntD, edgesS, edgesD);

    // LSTM + attention
    zx_kernel<<<768, 128, 0, stream>>>(queries, emb, Wih_f, bih_f, bhh_f, Wih_b, bih_b, bhh_b, zx);
    lstm_kernel<<<768, 128, 0, stream>>>(Whh_f, Whh_b, zx, hstate);
    attn_kernel<<<9, 128, 0, stream>>>(hstate, W0, b0, attn);

    // steps 0+1 sparse, step 2 dense
    hipMemsetAsync(mem2, 0, (size_t)NRANK * NENT * NB * sizeof(float), stream);
    {
        dim3 g(NB, NRANK);
        fused01_kernel<<<g, 128, 0, stream>>>(heads, attn, rpS, edgesS, mem2);
    }
    {
        dim3 g(NENT / 32, NPASS, NRANK);
        dense_kernel<<<g, 256, 0, stream>>>(attn, rpD, edgesD, mem2, mem3);
    }

    // epilogue
    hipMemsetAsync(normv, 0, NRANK * NB * sizeof(float), stream);
    {
        dim3 g(NENT / 320, NPASS, NRANK);
        norm_kernel<<<g, 256, 0, stream>>>(mem3, normv);
    }
    rnorm_kernel<<<1, NRANK * NB, 0, stream>>>(normv, rnormv);
    final_kernel<<<NENT / 32, 256, 0, stream>>>(mem3, rnormv, out);
}